// Round 4
// baseline (8204.419 us; speedup 1.0000x reference)
//
#include <hip/hip_runtime.h>
#include <hip/hip_bf16.h>
#include <stdint.h>

// AutoRegressive LSTM (B=1024, T=256, I=64, U=1024, S=64) on MI355X.
// R3: ONE persistent kernel for all 319 steps. Rows partitioned per-XCD
// (XCD k owns rows 128k..128k+127) so the recurrence never crosses an XCD:
// h lives in the local L2, c lives in registers, steps are separated by a
// 32-WG per-XCD barrier (L2-local atomics) instead of kernel launches.

typedef _Float16 f16;
typedef _Float16 f16x8 __attribute__((ext_vector_type(8)));
typedef float f32x4 __attribute__((ext_vector_type(4)));

#define NKW 17             // warmup K=1088 in BK=64 chunks
#define NKD 16             // decode K=1024
#define TILE_HALVES 8192   // 128x64 fp16 tile = 16KB

// element index inside a [rows][64] fp16 tile, XOR-swizzled (16B granule)
__device__ __forceinline__ int swz(int r, int k) { return (r * 64 + k) ^ ((r & 7) << 3); }

// stage one quarter (4KB) of a 16KB tile; wave w takes bytes [w*4096, w*4096+4096)
template <int AUX>
__device__ __forceinline__ void stage_q(const f16* __restrict__ g, f16* l, int w, int lane) {
  const char* gp = (const char*)g + w * 4096 + lane * 16;
  char* lp = (char*)l + w * 4096;
#pragma unroll
  for (int i = 0; i < 4; i++) {
    __builtin_amdgcn_global_load_lds(
        (const __attribute__((address_space(1))) unsigned int*)(gp + i * 1024),
        (__attribute__((address_space(3))) unsigned int*)(lp + i * 1024), 16, 0, AUX);
  }
}

__device__ __forceinline__ float sigf(float x) { return 1.0f / (1.0f + __expf(-x)); }
__device__ __forceinline__ float tanhfast(float x) { return 1.0f - 2.0f / (__expf(2.0f * x) + 1.0f); }

// ---------------- persistent LSTM kernel ----------------
// grid 256, block 256 (4 waves), 96KB LDS -> exactly 1 WG/CU, 32 WGs/XCD.
// mi = physical XCD id (rows 128*mi..+127), ni = per-XCD rank (units 32*ni..+31).
__global__ void __launch_bounds__(256, 1) lstm_persist(
    const f16* __restrict__ W16, const f16* __restrict__ WP16,
    const float* __restrict__ inputs,
    f16* __restrict__ hb0, f16* __restrict__ hb1, f16* __restrict__ xbuf,
    float* __restrict__ ppart,
    const float* __restrict__ bperm, const float* __restrict__ bperm2,
    const float* __restrict__ Wd, const float* __restrict__ bd,
    const int* __restrict__ oidx, float* __restrict__ out,
    int n_idx, unsigned* __restrict__ bar) {
  const int tid = threadIdx.x;

  __shared__ __align__(16) f16 As[3][TILE_HALVES];
  __shared__ __align__(16) f16 Bs[3][TILE_HALVES];
  __shared__ unsigned rank_sh;

  unsigned xcd;
  asm("s_getreg_b32 %0, hwreg(HW_REG_XCC_ID)" : "=s"(xcd));
  xcd &= 7u;
  unsigned* rank_ctr = bar;            // [xcd*16]
  unsigned* bar_cnt = bar + 128;       // [xcd*16]
  unsigned* bar_gen = bar + 256;       // [xcd*16]
  if (tid == 0)
    rank_sh = __hip_atomic_fetch_add(&rank_ctr[xcd * 16], 1u, __ATOMIC_RELAXED,
                                     __HIP_MEMORY_SCOPE_AGENT) & 31u;
  __syncthreads();
  const int mi = (int)xcd;
  const int ni = (int)rank_sh;

  const int w = tid >> 6, lane = tid & 63;
  const int rw = w >> 1, cw = w & 1, ln15 = lane & 15, ln4 = lane >> 4;
  const int u_glob = 32 * ni + 16 * cw + ln15;
  const int kkh = u_glob >> 6, kh = u_glob & 63;

  // preload biases + Wd columns for the output epilogue
  float biw[4], bi2[4];
#pragma unroll
  for (int nf = 0; nf < 4; nf++) {
    biw[nf] = bperm[ni * 128 + 64 * cw + 16 * nf + ln15];
    bi2[nf] = bperm2[ni * 128 + 64 * cw + 16 * nf + ln15];
  }
  float wdj[8];
#pragma unroll
  for (int j = 0; j < 8; j++) wdj[j] = 0.f;
  for (int j = 0; j < n_idx; j++) wdj[j] = Wd[(size_t)u_glob * 64 + oidx[j]];

  float cst[4][4];
#pragma unroll
  for (int a = 0; a < 4; a++)
#pragma unroll
    for (int q = 0; q < 4; q++) cst[a][q] = 0.f;

  for (int t = 0; t < 319; ++t) {
    // ---- per-XCD barrier: wait until all 32 WGs finished step t-1 ----
    if (tid == 0 && t > 0) {
      int guard = 0;
      while (__hip_atomic_load(&bar_gen[xcd * 16], __ATOMIC_RELAXED,
                               __HIP_MEMORY_SCOPE_AGENT) < (unsigned)t) {
        __builtin_amdgcn_s_sleep(2);
        if (++guard > (1 << 26)) break;   // safety valve: fail, don't hang
      }
    }
    __builtin_amdgcn_s_barrier();

    const bool warm = (t < 256);
    const int nk = warm ? NKW : NKD;
    const f16* Wb = warm ? (W16 + (size_t)ni * NKW * TILE_HALVES)
                         : (WP16 + (size_t)ni * NKD * TILE_HALVES);
    const f16* hin = (t & 1) ? hb1 : hb0;
    f16* hout = (t & 1) ? hb0 : hb1;
    const f16* hbase = hin + (size_t)mi * 16 * TILE_HALVES - (warm ? TILE_HALVES : 0);
    const f16* xb = xbuf + (size_t)((t & 1) * 8 + mi) * TILE_HALVES;

    // ---- distributed reduce of previous decode step's partials ----
    if (t >= 256) {
      const int s = t - 256;
      const int sb = (t - 1) & 1;
      if (tid < 4 * n_idx) {
        const int row = 4 * ni + (tid & 3);
        const int j = tid >> 2;
        float acc = bd[oidx[j]];
        for (int q = 0; q < 32; q++) {
#pragma unroll
          for (int c2 = 0; c2 < 2; c2++) {
            const size_t idx = ((((size_t)(sb * 8 + mi) * 32 + q) * 8 + j) * 2 + c2) * 128 + row;
            acc += __hip_atomic_load(&ppart[idx], __ATOMIC_RELAXED, __HIP_MEMORY_SCOPE_AGENT);
          }
        }
        out[((size_t)(128 * mi + row) * 64 + s) * n_idx + j] = acc;
      }
      asm volatile("s_waitcnt vmcnt(0)" ::: "memory");
    }

    // ---- stage chunks 0,1 ----
    stage_q<1>((warm ? xb : hbase), As[0], w, lane);
    stage_q<0>(Wb, Bs[0], w, lane);
    stage_q<1>(hbase + TILE_HALVES, As[1], w, lane);
    stage_q<0>(Wb + TILE_HALVES, Bs[1], w, lane);

    f32x4 acc[4][4];
#pragma unroll
    for (int a = 0; a < 4; a++)
#pragma unroll
      for (int q = 0; q < 4; q++) acc[a][q] = (f32x4){0.f, 0.f, 0.f, 0.f};

    // ---- K loop: 3-buf, counted vmcnt, one barrier per chunk ----
    for (int kk = 0; kk < nk; ++kk) {
      if (kk == nk - 1) asm volatile("s_waitcnt vmcnt(0)" ::: "memory");
      else              asm volatile("s_waitcnt vmcnt(8)" ::: "memory");
      __builtin_amdgcn_s_barrier();
      if (kk + 2 < nk) {
        const int b2 = (kk + 2) % 3;
        stage_q<1>(((kk + 2 == 0) ? xb : hbase + (size_t)(kk + 2) * TILE_HALVES), As[b2], w, lane);
        stage_q<0>(Wb + (size_t)(kk + 2) * TILE_HALVES, Bs[b2], w, lane);
      }
      const f16* Ab = As[kk % 3];
      const f16* Bb = Bs[kk % 3];
#pragma unroll
      for (int kc = 0; kc < 2; kc++) {
        const int kb = kc * 32 + ln4 * 8;
        f16x8 af[4], bf[4];
#pragma unroll
        for (int mf = 0; mf < 4; mf++)
          af[mf] = *(const f16x8*)(Ab + swz(64 * rw + 16 * mf + ln15, kb));
#pragma unroll
        for (int nf = 0; nf < 4; nf++)
          bf[nf] = *(const f16x8*)(Bb + swz(64 * cw + 16 * nf + ln15, kb));
        __builtin_amdgcn_s_setprio(1);
#pragma unroll
        for (int mf = 0; mf < 4; mf++)
#pragma unroll
          for (int nf = 0; nf < 4; nf++)
            acc[mf][nf] = __builtin_amdgcn_mfma_f32_16x16x32_f16(af[mf], bf[nf], acc[mf][nf], 0, 0, 0);
        __builtin_amdgcn_s_setprio(0);
      }
    }

    // ---- epilogue: gates -> c (regs), h (global, swizzled tiles) ----
    const float b0 = warm ? biw[0] : bi2[0];
    const float b1 = warm ? biw[1] : bi2[1];
    const float b2v = warm ? biw[2] : bi2[2];
    const float b3 = warm ? biw[3] : bi2[3];
    f16* ob = hout + ((size_t)mi * 16 + kkh) * TILE_HALVES;
    float hv[4][4];
#pragma unroll
    for (int mf = 0; mf < 4; mf++) {
#pragma unroll
      for (int reg = 0; reg < 4; reg++) {
        const int rl = 64 * rw + 16 * mf + 4 * ln4 + reg;
        const float zi = acc[mf][0][reg] + b0;
        const float zf = acc[mf][1][reg] + b1;
        const float zg = acc[mf][2][reg] + b2v;
        const float zo = acc[mf][3][reg] + b3;
        const float cn = sigf(zf) * cst[mf][reg] + sigf(zi) * tanhfast(zg);
        const float hn = sigf(zo) * tanhfast(cn);
        cst[mf][reg] = cn;
        hv[mf][reg] = hn;
        ob[swz(rl, kh)] = (f16)hn;
      }
    }

    // ---- decode partials: p_j contribution of this WG's 16-unit group ----
    if (t >= 255) {
      const int sbw = t & 1;
      for (int j = 0; j < n_idx; j++) {
        const float wd = wdj[j];
#pragma unroll
        for (int mf = 0; mf < 4; mf++)
#pragma unroll
          for (int reg = 0; reg < 4; reg++) {
            float v = hv[mf][reg] * wd;
            v += __shfl_xor(v, 1);
            v += __shfl_xor(v, 2);
            v += __shfl_xor(v, 4);
            v += __shfl_xor(v, 8);
            if (ln15 == 0) {
              const int rl = 64 * rw + 16 * mf + 4 * ln4 + reg;
              const size_t idx = ((((size_t)(sbw * 8 + mi) * 32 + ni) * 8 + j) * 2 + cw) * 128 + rl;
              ppart[idx] = v;
            }
          }
      }
    }

    // ---- x-tile prep for next warm step (rank 0 WG only) ----
    if (warm && (t + 1 < 256) && ni == 0) {
      const int r = tid >> 1, k0 = (tid & 1) * 32;
      const float* src = inputs + (size_t)(128 * mi + r) * 16384 + (size_t)(t + 1) * 64 + k0;
      f16* xo = xbuf + (size_t)(((t + 1) & 1) * 8 + mi) * TILE_HALVES;
#pragma unroll
      for (int q = 0; q < 4; q++) {
        const float4 a = *(const float4*)(src + q * 8);
        const float4 bq = *(const float4*)(src + q * 8 + 4);
        f16x8 v;
        v[0] = (f16)a.x; v[1] = (f16)a.y; v[2] = (f16)a.z; v[3] = (f16)a.w;
        v[4] = (f16)bq.x; v[5] = (f16)bq.y; v[6] = (f16)bq.z; v[7] = (f16)bq.w;
        *(f16x8*)(xo + swz(r, k0 + 8 * q)) = v;
      }
    }

    // ---- drain stores, arrive ----
    asm volatile("s_waitcnt vmcnt(0)" ::: "memory");
    __builtin_amdgcn_s_barrier();
    if (tid == 0) {
      unsigned old = __hip_atomic_fetch_add(&bar_cnt[xcd * 16], 1u, __ATOMIC_RELAXED,
                                            __HIP_MEMORY_SCOPE_AGENT);
      if ((old & 31u) == 31u)
        __hip_atomic_fetch_add(&bar_gen[xcd * 16], 1u, __ATOMIC_RELAXED,
                               __HIP_MEMORY_SCOPE_AGENT);
    }
  }

  // ---- final: reduce s=63 partials ----
  if (tid == 0) {
    int guard = 0;
    while (__hip_atomic_load(&bar_gen[xcd * 16], __ATOMIC_RELAXED,
                             __HIP_MEMORY_SCOPE_AGENT) < 319u) {
      __builtin_amdgcn_s_sleep(2);
      if (++guard > (1 << 26)) break;
    }
  }
  __builtin_amdgcn_s_barrier();
  if (tid < 4 * n_idx) {
    const int row = 4 * ni + (tid & 3);
    const int j = tid >> 2;
    const int sb = 318 & 1;  // = 0
    float acc = bd[oidx[j]];
    for (int q = 0; q < 32; q++) {
#pragma unroll
      for (int c2 = 0; c2 < 2; c2++) {
        const size_t idx = ((((size_t)(sb * 8 + mi) * 32 + q) * 8 + j) * 2 + c2) * 128 + row;
        acc += __hip_atomic_load(&ppart[idx], __ATOMIC_RELAXED, __HIP_MEMORY_SCOPE_AGENT);
      }
    }
    out[((size_t)(128 * mi + row) * 64 + 63) * n_idx + j] = acc;
  }
}

// ---------------- prep kernels ----------------
__global__ void __launch_bounds__(256) prep_W(const float* __restrict__ Wk,
                                              const float* __restrict__ Wr,
                                              f16* __restrict__ W16) {
  const int blk = blockIdx.x;  // ni*17 + kk
  const int ni = blk / NKW, kk = blk % NKW;
  f16* ob = W16 + (size_t)blk * TILE_HALVES;
  for (int c = threadIdx.x; c < 1024; c += 256) {
    const int n = c >> 3, k0 = (c & 7) * 8;
    const int nf = n >> 4, j = n & 15;
    const int gate = nf & 3;
    const int u = 32 * ni + 16 * (nf >> 2) + j;
    const int col = gate * 1024 + u;
    f16x8 v;
#pragma unroll
    for (int e = 0; e < 8; e++) {
      const int kr = kk * 64 + k0 + e;
      const float val = (kr < 64) ? Wk[(size_t)kr * 4096 + col]
                                  : Wr[(size_t)(kr - 64) * 4096 + col];
      v[e] = (f16)val;
    }
    *(f16x8*)(ob + swz(n, k0)) = v;
  }
}

// W' = Wd@Wk + Wr (decode fused weights)
__global__ void __launch_bounds__(256) prep_Wp(const float* __restrict__ Wk,
                                               const float* __restrict__ Wr,
                                               const float* __restrict__ Wd,
                                               f16* __restrict__ WP16) {
  const int blk = blockIdx.x;  // ni*16 + kk
  const int ni = blk / NKD, kk = blk % NKD;
  f16* ob = WP16 + (size_t)blk * TILE_HALVES;
  for (int c = threadIdx.x; c < 1024; c += 256) {
    const int n = c >> 3, k0 = (c & 7) * 8;
    const int nf = n >> 4, j = n & 15;
    const int gate = nf & 3;
    const int u = 32 * ni + 16 * (nf >> 2) + j;
    const int col = gate * 1024 + u;
    const int uh0 = kk * 64 + k0;
    float accv[8];
#pragma unroll
    for (int e = 0; e < 8; e++) accv[e] = Wr[(size_t)(uh0 + e) * 4096 + col];
#pragma unroll
    for (int i = 0; i < 64; i++) {
      const float wki = Wk[(size_t)i * 4096 + col];
#pragma unroll
      for (int e = 0; e < 8; e++)
        accv[e] += Wd[(size_t)(uh0 + e) * 64 + i] * wki;
    }
    f16x8 v;
#pragma unroll
    for (int e = 0; e < 8; e++) v[e] = (f16)accv[e];
    *(f16x8*)(ob + swz(n, k0)) = v;
  }
}

__global__ void __launch_bounds__(256) prep_b(const float* __restrict__ b, float* __restrict__ bperm) {
  const int x = blockIdx.x * 256 + threadIdx.x;  // 4096
  const int ni = x >> 7, rem = x & 127, nf = rem >> 4, j = rem & 15;
  bperm[x] = b[(nf & 3) * 1024 + 32 * ni + 16 * (nf >> 2) + j];
}

__global__ void __launch_bounds__(256) prep_b2(const float* __restrict__ b,
                                               const float* __restrict__ bd,
                                               const float* __restrict__ Wk,
                                               float* __restrict__ bperm2) {
  const int x = blockIdx.x * 256 + threadIdx.x;  // 4096
  const int ni = x >> 7, rem = x & 127, nf = rem >> 4, j = rem & 15;
  const int col = (nf & 3) * 1024 + 32 * ni + 16 * (nf >> 2) + j;
  float acc = b[col];
#pragma unroll
  for (int i = 0; i < 64; i++) acc += bd[i] * Wk[(size_t)i * 4096 + col];
  bperm2[x] = acc;
}

// x tile for t=0 into xbuf[0]
__global__ void __launch_bounds__(256) prep_x0(const float* __restrict__ inp, f16* __restrict__ xbuf) {
  const int mi = blockIdx.x, tid = threadIdx.x;
  const int r = tid >> 1, k0 = (tid & 1) * 32;
  const float* src = inp + (size_t)(128 * mi + r) * 16384 + k0;
  f16* ob = xbuf + (size_t)mi * TILE_HALVES;
#pragma unroll
  for (int q = 0; q < 4; q++) {
    const float4 a = *(const float4*)(src + q * 8);
    const float4 b = *(const float4*)(src + q * 8 + 4);
    f16x8 v;
    v[0] = (f16)a.x; v[1] = (f16)a.y; v[2] = (f16)a.z; v[3] = (f16)a.w;
    v[4] = (f16)b.x; v[5] = (f16)b.y; v[6] = (f16)b.z; v[7] = (f16)b.w;
    *(f16x8*)(ob + swz(r, k0 + 8 * q)) = v;
  }
}

// ---------------- host ----------------
extern "C" void kernel_launch(void* const* d_in, const int* in_sizes, int n_in,
                              void* d_out, int out_size, void* d_ws, size_t ws_size,
                              hipStream_t stream) {
  const float* inputs = (const float*)d_in[0];
  const float* Wk = (const float*)d_in[1];
  const float* Wr = (const float*)d_in[2];
  const float* bv = (const float*)d_in[3];
  const float* Wd = (const float*)d_in[4];
  const float* bd = (const float*)d_in[5];
  const int* oidx = (const int*)d_in[6];
  float* out = (float*)d_out;
  const int n_idx = out_size / (1024 * 64);
  if (n_idx < 1 || n_idx > 8) return;

  char* ws = (char*)d_ws;
  const size_t OFF_W16 = 0;                 // 8,912,896
  const size_t OFF_WP = 8912896;            // 8,388,608
  const size_t OFF_BPERM = 17301504;        // 16,384
  const size_t OFF_BPERM2 = 17317888;       // 16,384
  const size_t OFF_H0 = 17334272;           // 2,097,152
  const size_t OFF_H1 = 19431424;           // 2,097,152
  const size_t OFF_XB = 21528576;           // 262,144
  const size_t OFF_PP = 21790720;           // 4,194,304
  const size_t OFF_BAR = 25985024;          // 4,096
  const size_t NEED = 25989120;
  if (ws_size < NEED) return;

  f16* W16 = (f16*)(ws + OFF_W16);
  f16* WP16 = (f16*)(ws + OFF_WP);
  float* bperm = (float*)(ws + OFF_BPERM);
  float* bperm2 = (float*)(ws + OFF_BPERM2);
  f16* hb0 = (f16*)(ws + OFF_H0);
  f16* hb1 = (f16*)(ws + OFF_H1);
  f16* xbuf = (f16*)(ws + OFF_XB);
  float* ppart = (float*)(ws + OFF_PP);
  unsigned* bar = (unsigned*)(ws + OFF_BAR);

  hipMemsetAsync(hb0, 0, 2097152, stream);
  hipMemsetAsync(bar, 0, 4096, stream);
  hipLaunchKernelGGL(prep_W, dim3(544), dim3(256), 0, stream, Wk, Wr, W16);
  hipLaunchKernelGGL(prep_Wp, dim3(512), dim3(256), 0, stream, Wk, Wr, Wd, WP16);
  hipLaunchKernelGGL(prep_b, dim3(16), dim3(256), 0, stream, bv, bperm);
  hipLaunchKernelGGL(prep_b2, dim3(16), dim3(256), 0, stream, bv, bd, Wk, bperm2);
  hipLaunchKernelGGL(prep_x0, dim3(8), dim3(256), 0, stream, inputs, xbuf);

  hipLaunchKernelGGL(lstm_persist, dim3(256), dim3(256), 0, stream,
                     (const f16*)W16, (const f16*)WP16, inputs,
                     hb0, hb1, xbuf, ppart,
                     (const float*)bperm, (const float*)bperm2,
                     Wd, bd, oidx, out, n_idx, bar);
}